// Round 3
// baseline (884.699 us; speedup 1.0000x reference)
//
#include <hip/hip_runtime.h>
#include <math.h>

#define HW 65536

__device__ __forceinline__ float lrelu_f(float v) { return v > 0.f ? v : 0.2f * v; }

// ---- repack all weights: w[32][IC][KK] -> wr[IC][4][KK][8]  (one launch) ----
__global__ __launch_bounds__(256) void repack_all(
    const float* __restrict__ c1_w, float* __restrict__ wr_c1,
    const float* __restrict__ r1a_w, float* __restrict__ wr_r1a,
    const float* __restrict__ r1b_w, float* __restrict__ wr_r1b,
    const float* __restrict__ p1_w, float* __restrict__ wr_p1,
    const float* __restrict__ r2a_w, float* __restrict__ wr_r2a,
    const float* __restrict__ r2b_w, float* __restrict__ wr_r2b) {
  int i = blockIdx.x * 256 + threadIdx.x;
  const float* src;
  float* dst;
  int IC, KK, base;
  if (i < 2400)        { src = c1_w;  dst = wr_c1;  IC = 3;  KK = 25; base = 0; }
  else if (i < 11616)  { src = r1a_w; dst = wr_r1a; IC = 32; KK = 9;  base = 2400; }
  else if (i < 20832)  { src = r1b_w; dst = wr_r1b; IC = 32; KK = 9;  base = 11616; }
  else if (i < 72032)  { src = p1_w;  dst = wr_p1;  IC = 64; KK = 25; base = 20832; }
  else if (i < 81248)  { src = r2a_w; dst = wr_r2a; IC = 32; KK = 9;  base = 72032; }
  else if (i < 90464)  { src = r2b_w; dst = wr_r2b; IC = 32; KK = 9;  base = 81248; }
  else return;
  int j = i - base;
  int ickk = IC * KK;
  int o = j / ickk;
  int r = j - o * ickk;
  int ic = r / KK;
  int k = r - ic * KK;
  dst[((ic * 4 + (o >> 3)) * KK + k) * 8 + (o & 7)] = src[j];
}

// ---- bicubic 2x upsample: (2,3,128,128) -> (2,3,256,256) ----
__global__ __launch_bounds__(256) void up2_kernel(const float* __restrict__ q,
                                                  float* __restrict__ out) {
  int gid = blockIdx.x * blockDim.x + threadIdx.x;
  if (gid >= 2 * 3 * HW) return;
  int x = gid & 255;
  int y = (gid >> 8) & 255;
  int pc = gid >> 16;
  const float F[4] = {-0.03515625f, 0.26171875f, 0.87890625f, -0.10546875f};
  int iy[4], ix[4];
  float wy[4], wx[4];
  {
    int k = y >> 1; bool even = !(y & 1); int i0 = even ? k - 1 : k;
#pragma unroll
    for (int t = 0; t < 4; ++t) {
      int ii = i0 - 1 + t;
      iy[t] = min(max(ii, 0), 127);
      wy[t] = even ? F[t] : F[3 - t];
    }
  }
  {
    int k = x >> 1; bool even = !(x & 1); int i0 = even ? k - 1 : k;
#pragma unroll
    for (int t = 0; t < 4; ++t) {
      int ii = i0 - 1 + t;
      ix[t] = min(max(ii, 0), 127);
      wx[t] = even ? F[t] : F[3 - t];
    }
  }
  const float* qp = q + pc * 16384;
  float s = 0.f;
#pragma unroll
  for (int i = 0; i < 4; ++i) {
    float rs = 0.f;
#pragma unroll
    for (int j = 0; j < 4; ++j) rs = fmaf(wx[j], qp[iy[i] * 128 + ix[j]], rs);
    s = fmaf(wy[i], rs, s);
  }
  out[gid] = s;
}

// ============ conv kernels: 32x8 tile, 4 waves (2 rows each), 8 oc per BLOCK
// blk = b*1024 + ocg*256 + tile; tile: ty0=(tile>>3)*8, tx0=(tile&7)*32
// lane: py = 2*wv + (lane>>5), px = lane&31
// half-wave reads 32 consecutive LDS floats -> conflict-free at any stride.

// ---- conv 5x5, IC=3 -> 32, pad 2, + lrelu ----
__global__ __launch_bounds__(256) void conv5_c1(const float* __restrict__ in,
                                                const float* __restrict__ wr,
                                                const float* __restrict__ bias,
                                                float* __restrict__ out) {
  __shared__ float sm[3][12][36];  // 5184 B
  int blk = blockIdx.x;
  int b = blk >> 10;
  int ocg = (blk >> 8) & 3;
  int tile = blk & 255;
  int ty0 = (tile >> 3) * 8, tx0 = (tile & 7) * 32;
  int tid = threadIdx.x;
  for (int i = tid; i < 3 * 432; i += 256) {
    int ic = i / 432;
    int rem = i - ic * 432;
    int r = rem / 36;
    int c = rem - r * 36;
    int gy = ty0 + r - 2, gx = tx0 + c - 2;
    float v = 0.f;
    if ((unsigned)gy < 256u && (unsigned)gx < 256u) v = in[(b * 3 + ic) * HW + gy * 256 + gx];
    sm[ic][r][c] = v;
  }
  __syncthreads();
  int lane = tid & 63;
  int wv = __builtin_amdgcn_readfirstlane(tid >> 6);
  int py = 2 * wv + (lane >> 5), px = lane & 31;
  float acc[8];
#pragma unroll
  for (int o = 0; o < 8; ++o) acc[o] = bias[ocg * 8 + o];
#pragma unroll
  for (int ic = 0; ic < 3; ++ic) {
    const float* wp = wr + (ic * 4 + ocg) * 200;
#pragma unroll
    for (int ky = 0; ky < 5; ++ky)
#pragma unroll
      for (int kx = 0; kx < 5; ++kx) {
        float v = sm[ic][py + ky][px + kx];
        const float* w8 = wp + (ky * 5 + kx) * 8;
#pragma unroll
        for (int o = 0; o < 8; ++o) acc[o] = fmaf(v, w8[o], acc[o]);
      }
  }
  int y = ty0 + py, x = tx0 + px;
#pragma unroll
  for (int o = 0; o < 8; ++o)
    out[(b * 32 + ocg * 8 + o) * HW + y * 256 + x] = lrelu_f(acc[o]);
}

// ---- conv 3x3, 32 -> 32, pad 1, optional residual, lrelu (8-ic chunks) ----
template <bool RES>
__global__ __launch_bounds__(256) void conv3_32(const float* __restrict__ in, int in_cs,
                                                const float* __restrict__ wr,
                                                const float* __restrict__ bias,
                                                const float* __restrict__ res,
                                                float* __restrict__ out, int out_cs,
                                                int out_co) {
  __shared__ float sm[8][10][34];  // 10880 B
  int blk = blockIdx.x;
  int b = blk >> 10;
  int ocg = (blk >> 8) & 3;
  int tile = blk & 255;
  int ty0 = (tile >> 3) * 8, tx0 = (tile & 7) * 32;
  int tid = threadIdx.x;
  int lane = tid & 63;
  int wv = __builtin_amdgcn_readfirstlane(tid >> 6);
  int py = 2 * wv + (lane >> 5), px = lane & 31;
  float acc[8];
#pragma unroll
  for (int o = 0; o < 8; ++o) acc[o] = bias[ocg * 8 + o];
#pragma unroll 1
  for (int ch = 0; ch < 4; ++ch) {
    __syncthreads();
    for (int i = tid; i < 8 * 340; i += 256) {
      int ic = i / 340;
      int rem = i - ic * 340;
      int r = rem / 34;
      int c = rem - r * 34;
      int gy = ty0 + r - 1, gx = tx0 + c - 1;
      float v = 0.f;
      if ((unsigned)gy < 256u && (unsigned)gx < 256u)
        v = in[(b * in_cs + ch * 8 + ic) * HW + gy * 256 + gx];
      sm[ic][r][c] = v;
    }
    __syncthreads();
#pragma unroll 2
    for (int ic = 0; ic < 8; ++ic) {
      const float* wp = wr + ((ch * 8 + ic) * 4 + ocg) * 72;
#pragma unroll
      for (int ky = 0; ky < 3; ++ky)
#pragma unroll
        for (int kx = 0; kx < 3; ++kx) {
          float v = sm[ic][py + ky][px + kx];
          const float* w8 = wp + (ky * 3 + kx) * 8;
#pragma unroll
          for (int o = 0; o < 8; ++o) acc[o] = fmaf(v, w8[o], acc[o]);
        }
    }
  }
  int y = ty0 + py, x = tx0 + px;
  int co = out_co + ocg * 8;
#pragma unroll
  for (int o = 0; o < 8; ++o) {
    float rv = acc[o];
    if (RES) rv += res[(b * 32 + ocg * 8 + o) * HW + y * 256 + x];
    out[(b * out_cs + co + o) * HW + y * 256 + x] = lrelu_f(rv);
  }
}

// ---- conv 5x5, 64 -> 32, pad 2, + lrelu (8-ic chunks) ----
__global__ __launch_bounds__(256) void conv5_p1(const float* __restrict__ in,
                                                const float* __restrict__ wr,
                                                const float* __restrict__ bias,
                                                float* __restrict__ out) {
  __shared__ float sm[8][12][36];  // 13824 B
  int blk = blockIdx.x;
  int b = blk >> 10;
  int ocg = (blk >> 8) & 3;
  int tile = blk & 255;
  int ty0 = (tile >> 3) * 8, tx0 = (tile & 7) * 32;
  int tid = threadIdx.x;
  int lane = tid & 63;
  int wv = __builtin_amdgcn_readfirstlane(tid >> 6);
  int py = 2 * wv + (lane >> 5), px = lane & 31;
  float acc[8];
#pragma unroll
  for (int o = 0; o < 8; ++o) acc[o] = bias[ocg * 8 + o];
#pragma unroll 1
  for (int ch = 0; ch < 8; ++ch) {
    __syncthreads();
    for (int i = tid; i < 8 * 432; i += 256) {
      int ic = i / 432;
      int rem = i - ic * 432;
      int r = rem / 36;
      int c = rem - r * 36;
      int gy = ty0 + r - 2, gx = tx0 + c - 2;
      float v = 0.f;
      if ((unsigned)gy < 256u && (unsigned)gx < 256u)
        v = in[(b * 64 + ch * 8 + ic) * HW + gy * 256 + gx];
      sm[ic][r][c] = v;
    }
    __syncthreads();
#pragma unroll 2
    for (int ic = 0; ic < 8; ++ic) {
      const float* wp = wr + ((ch * 8 + ic) * 4 + ocg) * 200;
#pragma unroll
      for (int ky = 0; ky < 5; ++ky)
#pragma unroll
        for (int kx = 0; kx < 5; ++kx) {
          float v = sm[ic][py + ky][px + kx];
          const float* w8 = wp + (ky * 5 + kx) * 8;
#pragma unroll
          for (int o = 0; o < 8; ++o) acc[o] = fmaf(v, w8[o], acc[o]);
        }
    }
  }
  int y = ty0 + py, x = tx0 + px;
#pragma unroll
  for (int o = 0; o < 8; ++o)
    out[(b * 32 + ocg * 8 + o) * HW + y * 256 + x] = lrelu_f(acc[o]);
}

// ---- 1x1 conv 32->3, +1, clip, -> per-pixel sampling params ----
__global__ __launch_bounds__(256) void p2_aff(const float* __restrict__ h2,
                                              const float* __restrict__ w,
                                              const float* __restrict__ bias,
                                              float4* __restrict__ par) {
  int gid = blockIdx.x * 256 + threadIdx.x;  // 131072
  int b = gid >> 16;
  int p = gid & 65535;
  float a0 = bias[0], a1 = bias[1], a2 = bias[2];
  for (int c = 0; c < 32; ++c) {
    float v = h2[(b * 32 + c) * HW + p];
    a0 = fmaf(v, w[c], a0);
    a1 = fmaf(v, w[32 + c], a1);
    a2 = fmaf(v, w[64 + c], a2);
  }
  a0 = fminf(fmaxf(a0 + 1.f, -3.f), 3.f);
  a1 = fminf(fmaxf(a1 + 1.f, -3.f), 3.f);
  a2 = fminf(fmaxf(a2 + 1.f, -3.f), 3.f);
  float th = (a2 - 1.f) * 1.0472f;
  float4 o;
  o.x = a0;
  o.y = a1;
  o.z = cosf(th);
  o.w = sinf(th);
  par[gid] = o;
}

__device__ __forceinline__ int refl_idx(int k) {
  int s = k - 1;
  s = s < 0 ? -s : s;
  s = s > 255 ? 510 - s : s;
  return s;
}

// ---- deformable sampling: thread per (b, cgroup, y, xw); geometry once,
// reused across 8 channels; 9 taps -> 72 stores (L2 merges stride-3 rows) ----
__global__ __launch_bounds__(256) void sample_kernel(const float* __restrict__ x,
                                                     const float4* __restrict__ par,
                                                     float* __restrict__ out) {
  int gid = blockIdx.x * 256 + threadIdx.x;  // 524288
  int xw = gid & 255;
  int y = (gid >> 8) & 255;
  int cg = (gid >> 16) & 3;
  int b = gid >> 18;
  float4 pr = par[(b << 16) + y * 256 + xw];
  float sx = pr.x, sy = pr.y, ct = pr.z, st = pr.w;
  int off[9][4];
  float g[9][4];
#pragma unroll
  for (int ki = 0; ki < 3; ++ki)
#pragma unroll
    for (int kj = 0; kj < 3; ++kj) {
      int n = ki * 3 + kj;
      float px0 = ((float)ki - 1.5f) * sx;
      float py0 = ((float)kj - 1.5f) * sy;
      float px = px0 * ct - py0 * st + 1.5f + (float)(y + 1);
      float py = px0 * st + py0 * ct + 1.5f + (float)(xw + 1);
      float fx = floorf(px), fy = floorf(py);
      float x0f = fminf(fmaxf(fx, 0.f), 257.f);
      float x1f = fminf(fmaxf(fx + 1.f, 0.f), 257.f);
      float y0f = fminf(fmaxf(fy, 0.f), 257.f);
      float y1f = fminf(fmaxf(fy + 1.f, 0.f), 257.f);
      float pxc = fminf(fmaxf(px, 0.f), 257.f);
      float pyc = fminf(fmaxf(py, 0.f), 257.f);
      float dx0 = 1.f + (x0f - pxc), dx1 = 1.f - (x1f - pxc);
      float dy0 = 1.f + (y0f - pyc), dy1 = 1.f - (y1f - pyc);
      g[n][0] = dx0 * dy0;
      g[n][1] = dx1 * dy1;
      g[n][2] = dx0 * dy1;
      g[n][3] = dx1 * dy0;
      int xi0 = refl_idx((int)x0f), xi1 = refl_idx((int)x1f);
      int yi0 = refl_idx((int)y0f), yi1 = refl_idx((int)y1f);
      off[n][0] = xi0 * 256 + yi0;
      off[n][1] = xi1 * 256 + yi1;
      off[n][2] = xi0 * 256 + yi1;
      off[n][3] = xi1 * 256 + yi0;
    }
#pragma unroll 1
  for (int cc = 0; cc < 8; ++cc) {
    int c = cg * 8 + cc;
    const float* xp = x + (size_t)(b * 32 + c) * HW;
    float* op = out + ((size_t)(b * 32 + c) * 768 + 3 * y) * 768 + 3 * xw;
#pragma unroll
    for (int ki = 0; ki < 3; ++ki) {
#pragma unroll
      for (int kj = 0; kj < 3; ++kj) {
        int n = ki * 3 + kj;
        float v = g[n][0] * xp[off[n][0]] + g[n][1] * xp[off[n][1]] +
                  g[n][2] * xp[off[n][2]] + g[n][3] * xp[off[n][3]];
        op[ki * 768 + kj] = v;
      }
    }
  }
}

extern "C" void kernel_launch(void* const* d_in, const int* in_sizes, int n_in,
                              void* d_out, int out_size, void* d_ws, size_t ws_size,
                              hipStream_t stream) {
  const float* x = (const float*)d_in[0];
  const float* query = (const float*)d_in[1];
  const float* ref = (const float*)d_in[2];
  const float* c1_w = (const float*)d_in[3];
  const float* c1_b = (const float*)d_in[4];
  const float* r1a_w = (const float*)d_in[5];
  const float* r1a_b = (const float*)d_in[6];
  const float* r1b_w = (const float*)d_in[7];
  const float* r1b_b = (const float*)d_in[8];
  const float* p1_w = (const float*)d_in[9];
  const float* p1_b = (const float*)d_in[10];
  const float* r2a_w = (const float*)d_in[11];
  const float* r2a_b = (const float*)d_in[12];
  const float* r2b_w = (const float*)d_in[13];
  const float* r2b_b = (const float*)d_in[14];
  const float* p2_w = (const float*)d_in[15];
  const float* p2_b = (const float*)d_in[16];
  float* out = (float*)d_out;

  float* ws = (float*)d_ws;
  float* qup = ws;                        // 393216
  float* cat = qup + 393216;              // 8388608
  float* t1 = cat + 8388608;              // 4194304
  float* t2 = t1 + 4194304;               // 4194304
  float* h1 = t2 + 4194304;               // 4194304
  float4* par = (float4*)(h1 + 4194304);  // 131072 float4
  float* wr_c1 = (float*)(par + 131072);  // 2400
  float* wr_r1a = wr_c1 + 2400;           // 9216
  float* wr_r1b = wr_r1a + 9216;          // 9216
  float* wr_p1 = wr_r1b + 9216;           // 51200
  float* wr_r2a = wr_p1 + 51200;          // 9216
  float* wr_r2b = wr_r2a + 9216;          // 9216

  repack_all<<<354, 256, 0, stream>>>(c1_w, wr_c1, r1a_w, wr_r1a, r1b_w, wr_r1b,
                                      p1_w, wr_p1, r2a_w, wr_r2a, r2b_w, wr_r2b);

  up2_kernel<<<1536, 256, 0, stream>>>(query, qup);

  // head(ref) -> cat channels [0,32)
  conv5_c1<<<2048, 256, 0, stream>>>(ref, wr_c1, c1_b, t1);
  conv3_32<false><<<2048, 256, 0, stream>>>(t1, 32, wr_r1a, r1a_b, nullptr, t2, 32, 0);
  conv3_32<true><<<2048, 256, 0, stream>>>(t2, 32, wr_r1b, r1b_b, t1, cat, 64, 0);

  // head(q_up) -> cat channels [32,64)
  conv5_c1<<<2048, 256, 0, stream>>>(qup, wr_c1, c1_b, t1);
  conv3_32<false><<<2048, 256, 0, stream>>>(t1, 32, wr_r1a, r1a_b, nullptr, t2, 32, 0);
  conv3_32<true><<<2048, 256, 0, stream>>>(t2, 32, wr_r1b, r1b_b, t1, cat, 64, 32);

  // trunk
  conv5_p1<<<2048, 256, 0, stream>>>(cat, wr_p1, p1_b, h1);
  conv3_32<false><<<2048, 256, 0, stream>>>(h1, 32, wr_r2a, r2a_b, nullptr, t2, 32, 0);
  conv3_32<true><<<2048, 256, 0, stream>>>(t2, 32, wr_r2b, r2b_b, h1, t1, 32, 0);

  // affinity params
  p2_aff<<<512, 256, 0, stream>>>(t1, p2_w, p2_b, par);

  // deformable sampling
  sample_kernel<<<2048, 256, 0, stream>>>(x, par, out);
}

// Round 4
// 844.289 us; speedup vs baseline: 1.0479x; 1.0479x over previous
//
#include <hip/hip_runtime.h>
#include <math.h>

#define HW 65536

__device__ __forceinline__ float lrelu_f(float v) { return v > 0.f ? v : 0.2f * v; }

// ---- repack all weights: w[32][IC][KK] -> wr[IC][4][KK][8]  (one launch) ----
__global__ __launch_bounds__(256) void repack_all(
    const float* __restrict__ c1_w, float* __restrict__ wr_c1,
    const float* __restrict__ r1a_w, float* __restrict__ wr_r1a,
    const float* __restrict__ r1b_w, float* __restrict__ wr_r1b,
    const float* __restrict__ p1_w, float* __restrict__ wr_p1,
    const float* __restrict__ r2a_w, float* __restrict__ wr_r2a,
    const float* __restrict__ r2b_w, float* __restrict__ wr_r2b) {
  int i = blockIdx.x * 256 + threadIdx.x;
  const float* src;
  float* dst;
  int IC, KK, base;
  if (i < 2400)        { src = c1_w;  dst = wr_c1;  IC = 3;  KK = 25; base = 0; }
  else if (i < 11616)  { src = r1a_w; dst = wr_r1a; IC = 32; KK = 9;  base = 2400; }
  else if (i < 20832)  { src = r1b_w; dst = wr_r1b; IC = 32; KK = 9;  base = 11616; }
  else if (i < 72032)  { src = p1_w;  dst = wr_p1;  IC = 64; KK = 25; base = 20832; }
  else if (i < 81248)  { src = r2a_w; dst = wr_r2a; IC = 32; KK = 9;  base = 72032; }
  else if (i < 90464)  { src = r2b_w; dst = wr_r2b; IC = 32; KK = 9;  base = 81248; }
  else return;
  int j = i - base;
  int ickk = IC * KK;
  int o = j / ickk;
  int r = j - o * ickk;
  int ic = r / KK;
  int k = r - ic * KK;
  dst[((ic * 4 + (o >> 3)) * KK + k) * 8 + (o & 7)] = src[j];
}

// ---- bicubic 2x upsample: (2,3,128,128) -> (2,3,256,256) ----
__global__ __launch_bounds__(256) void up2_kernel(const float* __restrict__ q,
                                                  float* __restrict__ out) {
  int gid = blockIdx.x * blockDim.x + threadIdx.x;
  if (gid >= 2 * 3 * HW) return;
  int x = gid & 255;
  int y = (gid >> 8) & 255;
  int pc = gid >> 16;
  const float F[4] = {-0.03515625f, 0.26171875f, 0.87890625f, -0.10546875f};
  int iy[4], ix[4];
  float wy[4], wx[4];
  {
    int k = y >> 1; bool even = !(y & 1); int i0 = even ? k - 1 : k;
#pragma unroll
    for (int t = 0; t < 4; ++t) {
      int ii = i0 - 1 + t;
      iy[t] = min(max(ii, 0), 127);
      wy[t] = even ? F[t] : F[3 - t];
    }
  }
  {
    int k = x >> 1; bool even = !(x & 1); int i0 = even ? k - 1 : k;
#pragma unroll
    for (int t = 0; t < 4; ++t) {
      int ii = i0 - 1 + t;
      ix[t] = min(max(ii, 0), 127);
      wx[t] = even ? F[t] : F[3 - t];
    }
  }
  const float* qp = q + pc * 16384;
  float s = 0.f;
#pragma unroll
  for (int i = 0; i < 4; ++i) {
    float rs = 0.f;
#pragma unroll
    for (int j = 0; j < 4; ++j) rs = fmaf(wx[j], qp[iy[i] * 128 + ix[j]], rs);
    s = fmaf(wy[i], rs, s);
  }
  out[gid] = s;
}

// ============ conv kernels ============
// Tile 32x8 px per block; 256 threads = 4 waves; wave wv -> oc group wv (8 oc).
// Thread: 4 horizontal px x 8 oc (acc[4][8]); lane: row=lane>>3, colg=lane&7,
// px0=colg*4. LDS rows stride 40 floats, halo pre-shifted so window reads are
// two aligned ds_read_b128 at [px0] and [px0+4]. Weights via wave-uniform
// s_load from repacked wr.

// ---- conv 5x5, IC=3 -> 32, pad 2, + lrelu ----
__global__ __launch_bounds__(256) void conv5_c1(const float* __restrict__ in,
                                                const float* __restrict__ wr,
                                                const float* __restrict__ bias,
                                                float* __restrict__ out) {
  __shared__ float sm[3][12][40];
  int blk = blockIdx.x;
  int b = blk >> 8;
  int tile = blk & 255;
  int ty0 = (tile >> 3) * 8, tx0 = (tile & 7) * 32;
  int tid = threadIdx.x;
  for (int i = tid; i < 3 * 480; i += 256) {
    int ic = i / 480;
    int rem = i - ic * 480;
    int r = rem / 40;
    int c = rem - r * 40;
    int gy = ty0 + r - 2, gx = tx0 + c - 2;
    float v = 0.f;
    if ((unsigned)gy < 256u && (unsigned)gx < 256u) v = in[(b * 3 + ic) * HW + gy * 256 + gx];
    sm[ic][r][c] = v;
  }
  __syncthreads();
  int lane = tid & 63;
  int wv = __builtin_amdgcn_readfirstlane(tid >> 6);
  int row = lane >> 3, colg = lane & 7;
  int px0 = colg * 4;
  float acc[4][8];
#pragma unroll
  for (int j = 0; j < 4; ++j)
#pragma unroll
    for (int o = 0; o < 8; ++o) acc[j][o] = bias[wv * 8 + o];
#pragma unroll
  for (int ic = 0; ic < 3; ++ic) {
    const float* wp = wr + (ic * 4 + wv) * 200;
#pragma unroll
    for (int ky = 0; ky < 5; ++ky) {
      const float* srow = &sm[ic][row + ky][px0];
      float4 wa = *(const float4*)srow;
      float4 wb = *(const float4*)(srow + 4);
      float win[8] = {wa.x, wa.y, wa.z, wa.w, wb.x, wb.y, wb.z, wb.w};
#pragma unroll
      for (int kx = 0; kx < 5; ++kx) {
        const float* w8 = wp + (ky * 5 + kx) * 8;
#pragma unroll
        for (int o = 0; o < 8; ++o) {
          float wt = w8[o];
#pragma unroll
          for (int j = 0; j < 4; ++j) acc[j][o] = fmaf(win[j + kx], wt, acc[j][o]);
        }
      }
    }
  }
  int y = ty0 + row, x = tx0 + px0;
#pragma unroll
  for (int o = 0; o < 8; ++o) {
    float4 r4 = make_float4(lrelu_f(acc[0][o]), lrelu_f(acc[1][o]),
                            lrelu_f(acc[2][o]), lrelu_f(acc[3][o]));
    *(float4*)&out[(b * 32 + wv * 8 + o) * HW + y * 256 + x] = r4;
  }
}

// ---- conv 3x3, 32 -> 32, pad 1, optional residual, lrelu ----
template <bool RES>
__global__ __launch_bounds__(256) void conv3_32(const float* __restrict__ in, int in_cs,
                                                const float* __restrict__ wr,
                                                const float* __restrict__ bias,
                                                const float* __restrict__ res,
                                                float* __restrict__ out, int out_cs,
                                                int out_co) {
  __shared__ float sm[32][10][40];  // 51.2 KB, staged once
  int blk = blockIdx.x;
  int b = blk >> 8;
  int tile = blk & 255;
  int ty0 = (tile >> 3) * 8, tx0 = (tile & 7) * 32;
  int tid = threadIdx.x;
  for (int i = tid; i < 32 * 400; i += 256) {
    int ic = i / 400;
    int rem = i - ic * 400;
    int r = rem / 40;
    int c = rem - r * 40;
    int gy = ty0 + r - 1, gx = tx0 + c - 1;
    float v = 0.f;
    if ((unsigned)gy < 256u && (unsigned)gx < 256u)
      v = in[(b * in_cs + ic) * HW + gy * 256 + gx];
    sm[ic][r][c] = v;
  }
  __syncthreads();
  int lane = tid & 63;
  int wv = __builtin_amdgcn_readfirstlane(tid >> 6);
  int row = lane >> 3, colg = lane & 7;
  int px0 = colg * 4;
  float acc[4][8];
#pragma unroll
  for (int j = 0; j < 4; ++j)
#pragma unroll
    for (int o = 0; o < 8; ++o) acc[j][o] = bias[wv * 8 + o];
#pragma unroll 4
  for (int ic = 0; ic < 32; ++ic) {
    const float* wp = wr + (ic * 4 + wv) * 72;
#pragma unroll
    for (int ky = 0; ky < 3; ++ky) {
      const float* srow = &sm[ic][row + ky][px0];
      float4 wa = *(const float4*)srow;
      float4 wb = *(const float4*)(srow + 4);
      float win[8] = {wa.x, wa.y, wa.z, wa.w, wb.x, wb.y, wb.z, wb.w};
#pragma unroll
      for (int kx = 0; kx < 3; ++kx) {
        const float* w8 = wp + (ky * 3 + kx) * 8;
#pragma unroll
        for (int o = 0; o < 8; ++o) {
          float wt = w8[o];
#pragma unroll
          for (int j = 0; j < 4; ++j) acc[j][o] = fmaf(win[j + kx], wt, acc[j][o]);
        }
      }
    }
  }
  int y = ty0 + row, x = tx0 + px0;
  int co = out_co + wv * 8;
#pragma unroll
  for (int o = 0; o < 8; ++o) {
    float4 r4 = make_float4(acc[0][o], acc[1][o], acc[2][o], acc[3][o]);
    if (RES) {
      float4 rr = *(const float4*)&res[(b * 32 + wv * 8 + o) * HW + y * 256 + x];
      r4.x += rr.x; r4.y += rr.y; r4.z += rr.z; r4.w += rr.w;
    }
    r4.x = lrelu_f(r4.x); r4.y = lrelu_f(r4.y); r4.z = lrelu_f(r4.z); r4.w = lrelu_f(r4.w);
    *(float4*)&out[(b * out_cs + co + o) * HW + y * 256 + x] = r4;
  }
}

// ---- conv 5x5, 64 -> 32, pad 2, + lrelu (two 32-ic chunks) ----
__global__ __launch_bounds__(256) void conv5_p1(const float* __restrict__ in,
                                                const float* __restrict__ wr,
                                                const float* __restrict__ bias,
                                                float* __restrict__ out) {
  __shared__ float sm[32][12][40];  // 61.4 KB -> 2 blocks/CU
  int blk = blockIdx.x;
  int b = blk >> 8;
  int tile = blk & 255;
  int ty0 = (tile >> 3) * 8, tx0 = (tile & 7) * 32;
  int tid = threadIdx.x;
  int lane = tid & 63;
  int wv = __builtin_amdgcn_readfirstlane(tid >> 6);
  int row = lane >> 3, colg = lane & 7;
  int px0 = colg * 4;
  float acc[4][8];
#pragma unroll
  for (int j = 0; j < 4; ++j)
#pragma unroll
    for (int o = 0; o < 8; ++o) acc[j][o] = bias[wv * 8 + o];
#pragma unroll 1
  for (int ch = 0; ch < 2; ++ch) {
    __syncthreads();
    for (int i = tid; i < 32 * 480; i += 256) {
      int ic = i / 480;
      int rem = i - ic * 480;
      int r = rem / 40;
      int c = rem - r * 40;
      int gy = ty0 + r - 2, gx = tx0 + c - 2;
      float v = 0.f;
      if ((unsigned)gy < 256u && (unsigned)gx < 256u)
        v = in[(b * 64 + ch * 32 + ic) * HW + gy * 256 + gx];
      sm[ic][r][c] = v;
    }
    __syncthreads();
#pragma unroll 2
    for (int ic = 0; ic < 32; ++ic) {
      const float* wp = wr + ((ch * 32 + ic) * 4 + wv) * 200;
#pragma unroll
      for (int ky = 0; ky < 5; ++ky) {
        const float* srow = &sm[ic][row + ky][px0];
        float4 wa = *(const float4*)srow;
        float4 wb = *(const float4*)(srow + 4);
        float win[8] = {wa.x, wa.y, wa.z, wa.w, wb.x, wb.y, wb.z, wb.w};
#pragma unroll
        for (int kx = 0; kx < 5; ++kx) {
          const float* w8 = wp + (ky * 5 + kx) * 8;
#pragma unroll
          for (int o = 0; o < 8; ++o) {
            float wt = w8[o];
#pragma unroll
            for (int j = 0; j < 4; ++j) acc[j][o] = fmaf(win[j + kx], wt, acc[j][o]);
          }
        }
      }
    }
  }
  int y = ty0 + row, x = tx0 + px0;
#pragma unroll
  for (int o = 0; o < 8; ++o) {
    float4 r4 = make_float4(lrelu_f(acc[0][o]), lrelu_f(acc[1][o]),
                            lrelu_f(acc[2][o]), lrelu_f(acc[3][o]));
    *(float4*)&out[(b * 32 + wv * 8 + o) * HW + y * 256 + x] = r4;
  }
}

// ---- 1x1 conv 32->3, +1, clip, -> per-pixel sampling params ----
__global__ __launch_bounds__(256) void p2_aff(const float* __restrict__ h2,
                                              const float* __restrict__ w,
                                              const float* __restrict__ bias,
                                              float4* __restrict__ par) {
  int gid = blockIdx.x * 256 + threadIdx.x;  // 131072
  int b = gid >> 16;
  int p = gid & 65535;
  float a0 = bias[0], a1 = bias[1], a2 = bias[2];
  for (int c = 0; c < 32; ++c) {
    float v = h2[(b * 32 + c) * HW + p];
    a0 = fmaf(v, w[c], a0);
    a1 = fmaf(v, w[32 + c], a1);
    a2 = fmaf(v, w[64 + c], a2);
  }
  a0 = fminf(fmaxf(a0 + 1.f, -3.f), 3.f);
  a1 = fminf(fmaxf(a1 + 1.f, -3.f), 3.f);
  a2 = fminf(fmaxf(a2 + 1.f, -3.f), 3.f);
  float th = (a2 - 1.f) * 1.0472f;
  float4 o;
  o.x = a0;
  o.y = a1;
  o.z = cosf(th);
  o.w = sinf(th);
  par[gid] = o;
}

__device__ __forceinline__ int refl_idx(int k) {
  int s = k - 1;
  s = s < 0 ? -s : s;
  s = s > 255 ? 510 - s : s;
  return s;
}

// ---- deformable sampling: thread per (b, cgroup, y, xw); geometry once,
// reused across 8 channels ----
__global__ __launch_bounds__(256) void sample_kernel(const float* __restrict__ x,
                                                     const float4* __restrict__ par,
                                                     float* __restrict__ out) {
  int gid = blockIdx.x * 256 + threadIdx.x;  // 524288
  int xw = gid & 255;
  int y = (gid >> 8) & 255;
  int cg = (gid >> 16) & 3;
  int b = gid >> 18;
  float4 pr = par[(b << 16) + y * 256 + xw];
  float sx = pr.x, sy = pr.y, ct = pr.z, st = pr.w;
  int off[9][4];
  float g[9][4];
#pragma unroll
  for (int ki = 0; ki < 3; ++ki)
#pragma unroll
    for (int kj = 0; kj < 3; ++kj) {
      int n = ki * 3 + kj;
      float px0 = ((float)ki - 1.5f) * sx;
      float py0 = ((float)kj - 1.5f) * sy;
      float px = px0 * ct - py0 * st + 1.5f + (float)(y + 1);
      float py = px0 * st + py0 * ct + 1.5f + (float)(xw + 1);
      float fx = floorf(px), fy = floorf(py);
      float x0f = fminf(fmaxf(fx, 0.f), 257.f);
      float x1f = fminf(fmaxf(fx + 1.f, 0.f), 257.f);
      float y0f = fminf(fmaxf(fy, 0.f), 257.f);
      float y1f = fminf(fmaxf(fy + 1.f, 0.f), 257.f);
      float pxc = fminf(fmaxf(px, 0.f), 257.f);
      float pyc = fminf(fmaxf(py, 0.f), 257.f);
      float dx0 = 1.f + (x0f - pxc), dx1 = 1.f - (x1f - pxc);
      float dy0 = 1.f + (y0f - pyc), dy1 = 1.f - (y1f - pyc);
      g[n][0] = dx0 * dy0;
      g[n][1] = dx1 * dy1;
      g[n][2] = dx0 * dy1;
      g[n][3] = dx1 * dy0;
      int xi0 = refl_idx((int)x0f), xi1 = refl_idx((int)x1f);
      int yi0 = refl_idx((int)y0f), yi1 = refl_idx((int)y1f);
      off[n][0] = xi0 * 256 + yi0;
      off[n][1] = xi1 * 256 + yi1;
      off[n][2] = xi0 * 256 + yi1;
      off[n][3] = xi1 * 256 + yi0;
    }
#pragma unroll 1
  for (int cc = 0; cc < 8; ++cc) {
    int c = cg * 8 + cc;
    const float* xp = x + (size_t)(b * 32 + c) * HW;
    float* op = out + ((size_t)(b * 32 + c) * 768 + 3 * y) * 768 + 3 * xw;
#pragma unroll
    for (int ki = 0; ki < 3; ++ki) {
#pragma unroll
      for (int kj = 0; kj < 3; ++kj) {
        int n = ki * 3 + kj;
        float v = g[n][0] * xp[off[n][0]] + g[n][1] * xp[off[n][1]] +
                  g[n][2] * xp[off[n][2]] + g[n][3] * xp[off[n][3]];
        op[ki * 768 + kj] = v;
      }
    }
  }
}

extern "C" void kernel_launch(void* const* d_in, const int* in_sizes, int n_in,
                              void* d_out, int out_size, void* d_ws, size_t ws_size,
                              hipStream_t stream) {
  const float* x = (const float*)d_in[0];
  const float* query = (const float*)d_in[1];
  const float* ref = (const float*)d_in[2];
  const float* c1_w = (const float*)d_in[3];
  const float* c1_b = (const float*)d_in[4];
  const float* r1a_w = (const float*)d_in[5];
  const float* r1a_b = (const float*)d_in[6];
  const float* r1b_w = (const float*)d_in[7];
  const float* r1b_b = (const float*)d_in[8];
  const float* p1_w = (const float*)d_in[9];
  const float* p1_b = (const float*)d_in[10];
  const float* r2a_w = (const float*)d_in[11];
  const float* r2a_b = (const float*)d_in[12];
  const float* r2b_w = (const float*)d_in[13];
  const float* r2b_b = (const float*)d_in[14];
  const float* p2_w = (const float*)d_in[15];
  const float* p2_b = (const float*)d_in[16];
  float* out = (float*)d_out;

  float* ws = (float*)d_ws;
  float* qup = ws;                        // 393216
  float* cat = qup + 393216;              // 8388608
  float* t1 = cat + 8388608;              // 4194304
  float* t2 = t1 + 4194304;               // 4194304
  float* h1 = t2 + 4194304;               // 4194304
  float4* par = (float4*)(h1 + 4194304);  // 131072 float4
  float* wr_c1 = (float*)(par + 131072);  // 2400
  float* wr_r1a = wr_c1 + 2400;           // 9216
  float* wr_r1b = wr_r1a + 9216;          // 9216
  float* wr_p1 = wr_r1b + 9216;           // 51200
  float* wr_r2a = wr_p1 + 51200;          // 9216
  float* wr_r2b = wr_r2a + 9216;          // 9216

  repack_all<<<354, 256, 0, stream>>>(c1_w, wr_c1, r1a_w, wr_r1a, r1b_w, wr_r1b,
                                      p1_w, wr_p1, r2a_w, wr_r2a, r2b_w, wr_r2b);

  up2_kernel<<<1536, 256, 0, stream>>>(query, qup);

  // head(ref) -> cat channels [0,32)
  conv5_c1<<<512, 256, 0, stream>>>(ref, wr_c1, c1_b, t1);
  conv3_32<false><<<512, 256, 0, stream>>>(t1, 32, wr_r1a, r1a_b, nullptr, t2, 32, 0);
  conv3_32<true><<<512, 256, 0, stream>>>(t2, 32, wr_r1b, r1b_b, t1, cat, 64, 0);

  // head(q_up) -> cat channels [32,64)
  conv5_c1<<<512, 256, 0, stream>>>(qup, wr_c1, c1_b, t1);
  conv3_32<false><<<512, 256, 0, stream>>>(t1, 32, wr_r1a, r1a_b, nullptr, t2, 32, 0);
  conv3_32<true><<<512, 256, 0, stream>>>(t2, 32, wr_r1b, r1b_b, t1, cat, 64, 32);

  // trunk
  conv5_p1<<<512, 256, 0, stream>>>(cat, wr_p1, p1_b, h1);
  conv3_32<false><<<512, 256, 0, stream>>>(h1, 32, wr_r2a, r2a_b, nullptr, t2, 32, 0);
  conv3_32<true><<<512, 256, 0, stream>>>(t2, 32, wr_r2b, r2b_b, h1, t1, 32, 0);

  // affinity params
  p2_aff<<<512, 256, 0, stream>>>(t1, p2_w, p2_b, par);

  // deformable sampling
  sample_kernel<<<2048, 256, 0, stream>>>(x, par, out);
}

// Round 5
// 828.125 us; speedup vs baseline: 1.0683x; 1.0195x over previous
//
#include <hip/hip_runtime.h>
#include <math.h>

#define HW 65536

__device__ __forceinline__ float lrelu_f(float v) { return v > 0.f ? v : 0.2f * v; }

// ---- repack all weights: w[32][IC][KK] -> wr[IC][4][KK][8]  (one launch) ----
__global__ __launch_bounds__(256) void repack_all(
    const float* __restrict__ c1_w, float* __restrict__ wr_c1,
    const float* __restrict__ r1a_w, float* __restrict__ wr_r1a,
    const float* __restrict__ r1b_w, float* __restrict__ wr_r1b,
    const float* __restrict__ p1_w, float* __restrict__ wr_p1,
    const float* __restrict__ r2a_w, float* __restrict__ wr_r2a,
    const float* __restrict__ r2b_w, float* __restrict__ wr_r2b) {
  int i = blockIdx.x * 256 + threadIdx.x;
  const float* src;
  float* dst;
  int IC, KK, base;
  if (i < 2400)        { src = c1_w;  dst = wr_c1;  IC = 3;  KK = 25; base = 0; }
  else if (i < 11616)  { src = r1a_w; dst = wr_r1a; IC = 32; KK = 9;  base = 2400; }
  else if (i < 20832)  { src = r1b_w; dst = wr_r1b; IC = 32; KK = 9;  base = 11616; }
  else if (i < 72032)  { src = p1_w;  dst = wr_p1;  IC = 64; KK = 25; base = 20832; }
  else if (i < 81248)  { src = r2a_w; dst = wr_r2a; IC = 32; KK = 9;  base = 72032; }
  else if (i < 90464)  { src = r2b_w; dst = wr_r2b; IC = 32; KK = 9;  base = 81248; }
  else return;
  int j = i - base;
  int ickk = IC * KK;
  int o = j / ickk;
  int r = j - o * ickk;
  int ic = r / KK;
  int k = r - ic * KK;
  dst[((ic * 4 + (o >> 3)) * KK + k) * 8 + (o & 7)] = src[j];
}

// ---- bicubic 2x upsample: (2,3,128,128) -> (2,3,256,256) ----
__global__ __launch_bounds__(256) void up2_kernel(const float* __restrict__ q,
                                                  float* __restrict__ out) {
  int gid = blockIdx.x * blockDim.x + threadIdx.x;
  if (gid >= 2 * 3 * HW) return;
  int x = gid & 255;
  int y = (gid >> 8) & 255;
  int pc = gid >> 16;
  const float F[4] = {-0.03515625f, 0.26171875f, 0.87890625f, -0.10546875f};
  int iy[4], ix[4];
  float wy[4], wx[4];
  {
    int k = y >> 1; bool even = !(y & 1); int i0 = even ? k - 1 : k;
#pragma unroll
    for (int t = 0; t < 4; ++t) {
      int ii = i0 - 1 + t;
      iy[t] = min(max(ii, 0), 127);
      wy[t] = even ? F[t] : F[3 - t];
    }
  }
  {
    int k = x >> 1; bool even = !(x & 1); int i0 = even ? k - 1 : k;
#pragma unroll
    for (int t = 0; t < 4; ++t) {
      int ii = i0 - 1 + t;
      ix[t] = min(max(ii, 0), 127);
      wx[t] = even ? F[t] : F[3 - t];
    }
  }
  const float* qp = q + pc * 16384;
  float s = 0.f;
#pragma unroll
  for (int i = 0; i < 4; ++i) {
    float rs = 0.f;
#pragma unroll
    for (int j = 0; j < 4; ++j) rs = fmaf(wx[j], qp[iy[i] * 128 + ix[j]], rs);
    s = fmaf(wy[i], rs, s);
  }
  out[gid] = s;
}

// ============ conv kernels ============
// Tile 32x8 px per block; 256 threads = 4 waves; wave wv -> oc group wv (8 oc).
// Thread: 4 horizontal px x 8 oc (acc[4][8]); lane: row=lane>>3, colg=lane&7,
// px0=colg*4. LDS row stride 41 floats (odd): bank(lane,j) =
// (9*row + 4*colg + j) mod 32 -> all 32 lanes of each phase hit distinct banks
// (conflict-free b32/read2_b32; odd stride blocks b128 re-merge).

// ---- conv 5x5, IC=3 -> 32, pad 2, + lrelu ----
__global__ __launch_bounds__(256) void conv5_c1(const float* __restrict__ in,
                                                const float* __restrict__ wr,
                                                const float* __restrict__ bias,
                                                float* __restrict__ out) {
  __shared__ float sm[3][12][41];
  int blk = blockIdx.x;
  int b = blk >> 8;
  int tile = blk & 255;
  int ty0 = (tile >> 3) * 8, tx0 = (tile & 7) * 32;
  int tid = threadIdx.x;
  for (int i = tid; i < 3 * 12 * 36; i += 256) {
    int ic = i / 432;
    int rem = i - ic * 432;
    int r = rem / 36;
    int c = rem - r * 36;
    int gy = ty0 + r - 2, gx = tx0 + c - 2;
    float v = 0.f;
    if ((unsigned)gy < 256u && (unsigned)gx < 256u) v = in[(b * 3 + ic) * HW + gy * 256 + gx];
    sm[ic][r][c] = v;
  }
  __syncthreads();
  int lane = tid & 63;
  int wv = __builtin_amdgcn_readfirstlane(tid >> 6);
  int row = lane >> 3, colg = lane & 7;
  int px0 = colg * 4;
  float acc[4][8];
#pragma unroll
  for (int j = 0; j < 4; ++j)
#pragma unroll
    for (int o = 0; o < 8; ++o) acc[j][o] = bias[wv * 8 + o];
#pragma unroll
  for (int ic = 0; ic < 3; ++ic) {
    const float* wp = wr + (ic * 4 + wv) * 200;
#pragma unroll
    for (int ky = 0; ky < 5; ++ky) {
      const float* srow = &sm[ic][row + ky][px0];
      float win[8];
#pragma unroll
      for (int j = 0; j < 8; ++j) win[j] = srow[j];
#pragma unroll
      for (int kx = 0; kx < 5; ++kx) {
        const float* w8 = wp + (ky * 5 + kx) * 8;
#pragma unroll
        for (int o = 0; o < 8; ++o) {
          float wt = w8[o];
#pragma unroll
          for (int j = 0; j < 4; ++j) acc[j][o] = fmaf(win[j + kx], wt, acc[j][o]);
        }
      }
    }
  }
  int y = ty0 + row, x = tx0 + px0;
#pragma unroll
  for (int o = 0; o < 8; ++o) {
    float4 r4 = make_float4(lrelu_f(acc[0][o]), lrelu_f(acc[1][o]),
                            lrelu_f(acc[2][o]), lrelu_f(acc[3][o]));
    *(float4*)&out[(b * 32 + wv * 8 + o) * HW + y * 256 + x] = r4;
  }
}

// ---- conv 3x3, 32 -> 32, pad 1, optional residual, lrelu ----
template <bool RES>
__global__ __launch_bounds__(256) void conv3_32(const float* __restrict__ in, int in_cs,
                                                const float* __restrict__ wr,
                                                const float* __restrict__ bias,
                                                const float* __restrict__ res,
                                                float* __restrict__ out, int out_cs,
                                                int out_co) {
  __shared__ float sm[32][10][41];  // 52.5 KB, staged once, no inner barriers
  int blk = blockIdx.x;
  int b = blk >> 8;
  int tile = blk & 255;
  int ty0 = (tile >> 3) * 8, tx0 = (tile & 7) * 32;
  int tid = threadIdx.x;
  for (int i = tid; i < 32 * 10 * 34; i += 256) {
    int ic = i / 340;
    int rem = i - ic * 340;
    int r = rem / 34;
    int c = rem - r * 34;
    int gy = ty0 + r - 1, gx = tx0 + c - 1;
    float v = 0.f;
    if ((unsigned)gy < 256u && (unsigned)gx < 256u)
      v = in[(b * in_cs + ic) * HW + gy * 256 + gx];
    sm[ic][r][c] = v;
  }
  __syncthreads();
  int lane = tid & 63;
  int wv = __builtin_amdgcn_readfirstlane(tid >> 6);
  int row = lane >> 3, colg = lane & 7;
  int px0 = colg * 4;
  float acc[4][8];
#pragma unroll
  for (int j = 0; j < 4; ++j)
#pragma unroll
    for (int o = 0; o < 8; ++o) acc[j][o] = bias[wv * 8 + o];
#pragma unroll 4
  for (int ic = 0; ic < 32; ++ic) {
    const float* wp = wr + (ic * 4 + wv) * 72;
#pragma unroll
    for (int ky = 0; ky < 3; ++ky) {
      const float* srow = &sm[ic][row + ky][px0];
      float win[8];
#pragma unroll
      for (int j = 0; j < 8; ++j) win[j] = srow[j];
#pragma unroll
      for (int kx = 0; kx < 3; ++kx) {
        const float* w8 = wp + (ky * 3 + kx) * 8;
#pragma unroll
        for (int o = 0; o < 8; ++o) {
          float wt = w8[o];
#pragma unroll
          for (int j = 0; j < 4; ++j) acc[j][o] = fmaf(win[j + kx], wt, acc[j][o]);
        }
      }
    }
  }
  int y = ty0 + row, x = tx0 + px0;
  int co = out_co + wv * 8;
#pragma unroll
  for (int o = 0; o < 8; ++o) {
    float4 r4 = make_float4(acc[0][o], acc[1][o], acc[2][o], acc[3][o]);
    if (RES) {
      float4 rr = *(const float4*)&res[(b * 32 + wv * 8 + o) * HW + y * 256 + x];
      r4.x += rr.x; r4.y += rr.y; r4.z += rr.z; r4.w += rr.w;
    }
    r4.x = lrelu_f(r4.x); r4.y = lrelu_f(r4.y); r4.z = lrelu_f(r4.z); r4.w = lrelu_f(r4.w);
    *(float4*)&out[(b * out_cs + co + o) * HW + y * 256 + x] = r4;
  }
}

// ---- conv 5x5, 64 -> 32, pad 2, + lrelu (two 32-ic chunks) ----
__global__ __launch_bounds__(256) void conv5_p1(const float* __restrict__ in,
                                                const float* __restrict__ wr,
                                                const float* __restrict__ bias,
                                                float* __restrict__ out) {
  __shared__ float sm[32][12][41];  // 63 KB
  int blk = blockIdx.x;
  int b = blk >> 8;
  int tile = blk & 255;
  int ty0 = (tile >> 3) * 8, tx0 = (tile & 7) * 32;
  int tid = threadIdx.x;
  int lane = tid & 63;
  int wv = __builtin_amdgcn_readfirstlane(tid >> 6);
  int row = lane >> 3, colg = lane & 7;
  int px0 = colg * 4;
  float acc[4][8];
#pragma unroll
  for (int j = 0; j < 4; ++j)
#pragma unroll
    for (int o = 0; o < 8; ++o) acc[j][o] = bias[wv * 8 + o];
#pragma unroll 1
  for (int ch = 0; ch < 2; ++ch) {
    __syncthreads();
    for (int i = tid; i < 32 * 12 * 36; i += 256) {
      int ic = i / 432;
      int rem = i - ic * 432;
      int r = rem / 36;
      int c = rem - r * 36;
      int gy = ty0 + r - 2, gx = tx0 + c - 2;
      float v = 0.f;
      if ((unsigned)gy < 256u && (unsigned)gx < 256u)
        v = in[(b * 64 + ch * 32 + ic) * HW + gy * 256 + gx];
      sm[ic][r][c] = v;
    }
    __syncthreads();
#pragma unroll 2
    for (int ic = 0; ic < 32; ++ic) {
      const float* wp = wr + ((ch * 32 + ic) * 4 + wv) * 200;
#pragma unroll
      for (int ky = 0; ky < 5; ++ky) {
        const float* srow = &sm[ic][row + ky][px0];
        float win[8];
#pragma unroll
        for (int j = 0; j < 8; ++j) win[j] = srow[j];
#pragma unroll
        for (int kx = 0; kx < 5; ++kx) {
          const float* w8 = wp + (ky * 5 + kx) * 8;
#pragma unroll
          for (int o = 0; o < 8; ++o) {
            float wt = w8[o];
#pragma unroll
            for (int j = 0; j < 4; ++j) acc[j][o] = fmaf(win[j + kx], wt, acc[j][o]);
          }
        }
      }
    }
  }
  int y = ty0 + row, x = tx0 + px0;
#pragma unroll
  for (int o = 0; o < 8; ++o) {
    float4 r4 = make_float4(lrelu_f(acc[0][o]), lrelu_f(acc[1][o]),
                            lrelu_f(acc[2][o]), lrelu_f(acc[3][o]));
    *(float4*)&out[(b * 32 + wv * 8 + o) * HW + y * 256 + x] = r4;
  }
}

// ---- 1x1 conv 32->3, +1, clip, -> per-pixel sampling params ----
__global__ __launch_bounds__(256) void p2_aff(const float* __restrict__ h2,
                                              const float* __restrict__ w,
                                              const float* __restrict__ bias,
                                              float4* __restrict__ par) {
  int gid = blockIdx.x * 256 + threadIdx.x;  // 131072
  int b = gid >> 16;
  int p = gid & 65535;
  float a0 = bias[0], a1 = bias[1], a2 = bias[2];
  for (int c = 0; c < 32; ++c) {
    float v = h2[(b * 32 + c) * HW + p];
    a0 = fmaf(v, w[c], a0);
    a1 = fmaf(v, w[32 + c], a1);
    a2 = fmaf(v, w[64 + c], a2);
  }
  a0 = fminf(fmaxf(a0 + 1.f, -3.f), 3.f);
  a1 = fminf(fmaxf(a1 + 1.f, -3.f), 3.f);
  a2 = fminf(fmaxf(a2 + 1.f, -3.f), 3.f);
  float th = (a2 - 1.f) * 1.0472f;
  float4 o;
  o.x = a0;
  o.y = a1;
  o.z = cosf(th);
  o.w = sinf(th);
  par[gid] = o;
}

__device__ __forceinline__ int refl_idx(int k) {
  int s = k - 1;
  s = s < 0 ? -s : s;
  s = s > 255 ? 510 - s : s;
  return s;
}

// ---- deformable sampling: thread per (b, cgroup, y, xw); geometry once,
// reused across 8 channels ----
__global__ __launch_bounds__(256) void sample_kernel(const float* __restrict__ x,
                                                     const float4* __restrict__ par,
                                                     float* __restrict__ out) {
  int gid = blockIdx.x * 256 + threadIdx.x;  // 524288
  int xw = gid & 255;
  int y = (gid >> 8) & 255;
  int cg = (gid >> 16) & 3;
  int b = gid >> 18;
  float4 pr = par[(b << 16) + y * 256 + xw];
  float sx = pr.x, sy = pr.y, ct = pr.z, st = pr.w;
  int off[9][4];
  float g[9][4];
#pragma unroll
  for (int ki = 0; ki < 3; ++ki)
#pragma unroll
    for (int kj = 0; kj < 3; ++kj) {
      int n = ki * 3 + kj;
      float px0 = ((float)ki - 1.5f) * sx;
      float py0 = ((float)kj - 1.5f) * sy;
      float px = px0 * ct - py0 * st + 1.5f + (float)(y + 1);
      float py = px0 * st + py0 * ct + 1.5f + (float)(xw + 1);
      float fx = floorf(px), fy = floorf(py);
      float x0f = fminf(fmaxf(fx, 0.f), 257.f);
      float x1f = fminf(fmaxf(fx + 1.f, 0.f), 257.f);
      float y0f = fminf(fmaxf(fy, 0.f), 257.f);
      float y1f = fminf(fmaxf(fy + 1.f, 0.f), 257.f);
      float pxc = fminf(fmaxf(px, 0.f), 257.f);
      float pyc = fminf(fmaxf(py, 0.f), 257.f);
      float dx0 = 1.f + (x0f - pxc), dx1 = 1.f - (x1f - pxc);
      float dy0 = 1.f + (y0f - pyc), dy1 = 1.f - (y1f - pyc);
      g[n][0] = dx0 * dy0;
      g[n][1] = dx1 * dy1;
      g[n][2] = dx0 * dy1;
      g[n][3] = dx1 * dy0;
      int xi0 = refl_idx((int)x0f), xi1 = refl_idx((int)x1f);
      int yi0 = refl_idx((int)y0f), yi1 = refl_idx((int)y1f);
      off[n][0] = xi0 * 256 + yi0;
      off[n][1] = xi1 * 256 + yi1;
      off[n][2] = xi0 * 256 + yi1;
      off[n][3] = xi1 * 256 + yi0;
    }
#pragma unroll 1
  for (int cc = 0; cc < 8; ++cc) {
    int c = cg * 8 + cc;
    const float* xp = x + (size_t)(b * 32 + c) * HW;
    float* op = out + ((size_t)(b * 32 + c) * 768 + 3 * y) * 768 + 3 * xw;
#pragma unroll
    for (int ki = 0; ki < 3; ++ki) {
#pragma unroll
      for (int kj = 0; kj < 3; ++kj) {
        int n = ki * 3 + kj;
        float v = g[n][0] * xp[off[n][0]] + g[n][1] * xp[off[n][1]] +
                  g[n][2] * xp[off[n][2]] + g[n][3] * xp[off[n][3]];
        op[ki * 768 + kj] = v;
      }
    }
  }
}

extern "C" void kernel_launch(void* const* d_in, const int* in_sizes, int n_in,
                              void* d_out, int out_size, void* d_ws, size_t ws_size,
                              hipStream_t stream) {
  const float* x = (const float*)d_in[0];
  const float* query = (const float*)d_in[1];
  const float* ref = (const float*)d_in[2];
  const float* c1_w = (const float*)d_in[3];
  const float* c1_b = (const float*)d_in[4];
  const float* r1a_w = (const float*)d_in[5];
  const float* r1a_b = (const float*)d_in[6];
  const float* r1b_w = (const float*)d_in[7];
  const float* r1b_b = (const float*)d_in[8];
  const float* p1_w = (const float*)d_in[9];
  const float* p1_b = (const float*)d_in[10];
  const float* r2a_w = (const float*)d_in[11];
  const float* r2a_b = (const float*)d_in[12];
  const float* r2b_w = (const float*)d_in[13];
  const float* r2b_b = (const float*)d_in[14];
  const float* p2_w = (const float*)d_in[15];
  const float* p2_b = (const float*)d_in[16];
  float* out = (float*)d_out;

  float* ws = (float*)d_ws;
  float* qup = ws;                        // 393216
  float* cat = qup + 393216;              // 8388608
  float* t1 = cat + 8388608;              // 4194304
  float* t2 = t1 + 4194304;               // 4194304
  float* h1 = t2 + 4194304;               // 4194304
  float4* par = (float4*)(h1 + 4194304);  // 131072 float4
  float* wr_c1 = (float*)(par + 131072);  // 2400
  float* wr_r1a = wr_c1 + 2400;           // 9216
  float* wr_r1b = wr_r1a + 9216;          // 9216
  float* wr_p1 = wr_r1b + 9216;           // 51200
  float* wr_r2a = wr_p1 + 51200;          // 9216
  float* wr_r2b = wr_r2a + 9216;          // 9216

  repack_all<<<354, 256, 0, stream>>>(c1_w, wr_c1, r1a_w, wr_r1a, r1b_w, wr_r1b,
                                      p1_w, wr_p1, r2a_w, wr_r2a, r2b_w, wr_r2b);

  up2_kernel<<<1536, 256, 0, stream>>>(query, qup);

  // head(ref) -> cat channels [0,32)
  conv5_c1<<<512, 256, 0, stream>>>(ref, wr_c1, c1_b, t1);
  conv3_32<false><<<512, 256, 0, stream>>>(t1, 32, wr_r1a, r1a_b, nullptr, t2, 32, 0);
  conv3_32<true><<<512, 256, 0, stream>>>(t2, 32, wr_r1b, r1b_b, t1, cat, 64, 0);

  // head(q_up) -> cat channels [32,64)
  conv5_c1<<<512, 256, 0, stream>>>(qup, wr_c1, c1_b, t1);
  conv3_32<false><<<512, 256, 0, stream>>>(t1, 32, wr_r1a, r1a_b, nullptr, t2, 32, 0);
  conv3_32<true><<<512, 256, 0, stream>>>(t2, 32, wr_r1b, r1b_b, t1, cat, 64, 32);

  // trunk
  conv5_p1<<<512, 256, 0, stream>>>(cat, wr_p1, p1_b, h1);
  conv3_32<false><<<512, 256, 0, stream>>>(h1, 32, wr_r2a, r2a_b, nullptr, t2, 32, 0);
  conv3_32<true><<<512, 256, 0, stream>>>(t2, 32, wr_r2b, r2b_b, h1, t1, 32, 0);

  // affinity params
  p2_aff<<<512, 256, 0, stream>>>(t1, p2_w, p2_b, par);

  // deformable sampling
  sample_kernel<<<2048, 256, 0, stream>>>(x, par, out);
}

// Round 7
// 739.786 us; speedup vs baseline: 1.1959x; 1.1194x over previous
//
#include <hip/hip_runtime.h>
#include <math.h>

#define HW 65536

__device__ __forceinline__ float lrelu_f(float v) { return v > 0.f ? v : 0.2f * v; }

// ---- repack all weights: w[32][IC][KK] -> wr[IC][4][KK][8]  (one launch) ----
__global__ __launch_bounds__(256) void repack_all(
    const float* __restrict__ c1_w, float* __restrict__ wr_c1,
    const float* __restrict__ r1a_w, float* __restrict__ wr_r1a,
    const float* __restrict__ r1b_w, float* __restrict__ wr_r1b,
    const float* __restrict__ p1_w, float* __restrict__ wr_p1,
    const float* __restrict__ r2a_w, float* __restrict__ wr_r2a,
    const float* __restrict__ r2b_w, float* __restrict__ wr_r2b) {
  int i = blockIdx.x * 256 + threadIdx.x;
  const float* src;
  float* dst;
  int IC, KK, base;
  if (i < 2400)        { src = c1_w;  dst = wr_c1;  IC = 3;  KK = 25; base = 0; }
  else if (i < 11616)  { src = r1a_w; dst = wr_r1a; IC = 32; KK = 9;  base = 2400; }
  else if (i < 20832)  { src = r1b_w; dst = wr_r1b; IC = 32; KK = 9;  base = 11616; }
  else if (i < 72032)  { src = p1_w;  dst = wr_p1;  IC = 64; KK = 25; base = 20832; }
  else if (i < 81248)  { src = r2a_w; dst = wr_r2a; IC = 32; KK = 9;  base = 72032; }
  else if (i < 90464)  { src = r2b_w; dst = wr_r2b; IC = 32; KK = 9;  base = 81248; }
  else return;
  int j = i - base;
  int ickk = IC * KK;
  int o = j / ickk;
  int r = j - o * ickk;
  int ic = r / KK;
  int k = r - ic * KK;
  dst[((ic * 4 + (o >> 3)) * KK + k) * 8 + (o & 7)] = src[j];
}

// ---- bicubic 2x upsample: (2,3,128,128) -> (2,3,256,256) ----
__global__ __launch_bounds__(256) void up2_kernel(const float* __restrict__ q,
                                                  float* __restrict__ out) {
  int gid = blockIdx.x * blockDim.x + threadIdx.x;
  if (gid >= 2 * 3 * HW) return;
  int x = gid & 255;
  int y = (gid >> 8) & 255;
  int pc = gid >> 16;
  const float F[4] = {-0.03515625f, 0.26171875f, 0.87890625f, -0.10546875f};
  int iy[4], ix[4];
  float wy[4], wx[4];
  {
    int k = y >> 1; bool even = !(y & 1); int i0 = even ? k - 1 : k;
#pragma unroll
    for (int t = 0; t < 4; ++t) {
      int ii = i0 - 1 + t;
      iy[t] = min(max(ii, 0), 127);
      wy[t] = even ? F[t] : F[3 - t];
    }
  }
  {
    int k = x >> 1; bool even = !(x & 1); int i0 = even ? k - 1 : k;
#pragma unroll
    for (int t = 0; t < 4; ++t) {
      int ii = i0 - 1 + t;
      ix[t] = min(max(ii, 0), 127);
      wx[t] = even ? F[t] : F[3 - t];
    }
  }
  const float* qp = q + pc * 16384;
  float s = 0.f;
#pragma unroll
  for (int i = 0; i < 4; ++i) {
    float rs = 0.f;
#pragma unroll
    for (int j = 0; j < 4; ++j) rs = fmaf(wx[j], qp[iy[i] * 128 + ix[j]], rs);
    s = fmaf(wy[i], rs, s);
  }
  out[gid] = s;
}

// ============ conv kernels ============
// Tile 32x4 px per block; grid 1024 (4 blocks/CU); 256 threads = 4 waves;
// wave wv -> oc group (8 oc). Thread: 2 horizontal px x 8 oc (acc[2][8]).
// lane: row = lane>>4 (0..3), colg = lane&15, px0 = 2*colg.
// LDS row stride 37 (odd): bank = (5*row + 2*colg + j) mod 32 -> each
// half-wave phase hits 32 distinct banks (measured-zero-conflict family).

// ---- conv 5x5, IC=3 -> 32, pad 2, + lrelu ----
__global__ __launch_bounds__(256, 4) void conv5_c1(const float* __restrict__ in,
                                                   const float* __restrict__ wr,
                                                   const float* __restrict__ bias,
                                                   float* __restrict__ out) {
  __shared__ float sm[3][8][37];
  int blk = blockIdx.x;
  int b = blk >> 9;
  int t = blk & 511;
  int ty0 = (t >> 3) * 4, tx0 = (t & 7) * 32;
  int tid = threadIdx.x;
  for (int i = tid; i < 3 * 8 * 36; i += 256) {
    int ic = i / 288;
    int rem = i - ic * 288;
    int r = rem / 36;
    int c = rem - r * 36;
    int gy = ty0 + r - 2, gx = tx0 + c - 2;
    float v = 0.f;
    if ((unsigned)gy < 256u && (unsigned)gx < 256u) v = in[(b * 3 + ic) * HW + gy * 256 + gx];
    sm[ic][r][c] = v;
  }
  __syncthreads();
  int lane = tid & 63;
  int wv = __builtin_amdgcn_readfirstlane(tid >> 6);
  int row = lane >> 4, colg = lane & 15;
  int px0 = colg * 2;
  float acc[2][8];
#pragma unroll
  for (int j = 0; j < 2; ++j)
#pragma unroll
    for (int o = 0; o < 8; ++o) acc[j][o] = bias[wv * 8 + o];
#pragma unroll
  for (int ic = 0; ic < 3; ++ic) {
    const float* wp = wr + (ic * 4 + wv) * 200;
#pragma unroll
    for (int ky = 0; ky < 5; ++ky) {
      const float* srow = &sm[ic][row + ky][px0];
      float win[6];
#pragma unroll
      for (int j = 0; j < 6; ++j) win[j] = srow[j];
#pragma unroll
      for (int kx = 0; kx < 5; ++kx) {
        const float* w8 = wp + (ky * 5 + kx) * 8;
#pragma unroll
        for (int o = 0; o < 8; ++o) {
          float wt = w8[o];
          acc[0][o] = fmaf(win[kx], wt, acc[0][o]);
          acc[1][o] = fmaf(win[kx + 1], wt, acc[1][o]);
        }
      }
    }
  }
  int y = ty0 + row, x = tx0 + px0;
#pragma unroll
  for (int o = 0; o < 8; ++o) {
    float2 r2 = make_float2(lrelu_f(acc[0][o]), lrelu_f(acc[1][o]));
    *(float2*)&out[(b * 32 + wv * 8 + o) * HW + y * 256 + x] = r2;
  }
}

// ---- conv 3x3, 32 -> 32, pad 1, optional residual, lrelu ----
template <bool RES>
__global__ __launch_bounds__(256, 4) void conv3_32(const float* __restrict__ in, int in_cs,
                                                   const float* __restrict__ wr,
                                                   const float* __restrict__ bias,
                                                   const float* __restrict__ res,
                                                   float* __restrict__ out, int out_cs,
                                                   int out_co) {
  __shared__ float sm[32][6][37];  // 28.4 KB, staged once, no inner barriers
  int blk = blockIdx.x;
  int b = blk >> 9;
  int t = blk & 511;
  int ty0 = (t >> 3) * 4, tx0 = (t & 7) * 32;
  int tid = threadIdx.x;
  for (int i = tid; i < 32 * 6 * 34; i += 256) {
    int ic = i / 204;
    int rem = i - ic * 204;
    int r = rem / 34;
    int c = rem - r * 34;
    int gy = ty0 + r - 1, gx = tx0 + c - 1;
    float v = 0.f;
    if ((unsigned)gy < 256u && (unsigned)gx < 256u)
      v = in[(b * in_cs + ic) * HW + gy * 256 + gx];
    sm[ic][r][c] = v;
  }
  __syncthreads();
  int lane = tid & 63;
  int wv = __builtin_amdgcn_readfirstlane(tid >> 6);
  int row = lane >> 4, colg = lane & 15;
  int px0 = colg * 2;
  float acc[2][8];
#pragma unroll
  for (int j = 0; j < 2; ++j)
#pragma unroll
    for (int o = 0; o < 8; ++o) acc[j][o] = bias[wv * 8 + o];
#pragma unroll 4
  for (int ic = 0; ic < 32; ++ic) {
    const float* wp = wr + (ic * 4 + wv) * 72;
#pragma unroll
    for (int ky = 0; ky < 3; ++ky) {
      const float* srow = &sm[ic][row + ky][px0];
      float win[4];
#pragma unroll
      for (int j = 0; j < 4; ++j) win[j] = srow[j];
#pragma unroll
      for (int kx = 0; kx < 3; ++kx) {
        const float* w8 = wp + (ky * 3 + kx) * 8;
#pragma unroll
        for (int o = 0; o < 8; ++o) {
          float wt = w8[o];
          acc[0][o] = fmaf(win[kx], wt, acc[0][o]);
          acc[1][o] = fmaf(win[kx + 1], wt, acc[1][o]);
        }
      }
    }
  }
  int y = ty0 + row, x = tx0 + px0;
  int co = out_co + wv * 8;
#pragma unroll
  for (int o = 0; o < 8; ++o) {
    float2 r2 = make_float2(acc[0][o], acc[1][o]);
    if (RES) {
      float2 rr = *(const float2*)&res[(b * 32 + wv * 8 + o) * HW + y * 256 + x];
      r2.x += rr.x; r2.y += rr.y;
    }
    r2.x = lrelu_f(r2.x); r2.y = lrelu_f(r2.y);
    *(float2*)&out[(b * out_cs + co + o) * HW + y * 256 + x] = r2;
  }
}

// ---- conv 5x5, 64 -> 32, pad 2, + lrelu (two 32-ic chunks) ----
__global__ __launch_bounds__(256, 4) void conv5_p1(const float* __restrict__ in,
                                                   const float* __restrict__ wr,
                                                   const float* __restrict__ bias,
                                                   float* __restrict__ out) {
  __shared__ float sm[32][8][37];  // 37.9 KB -> 4 blocks/CU
  int blk = blockIdx.x;
  int b = blk >> 9;
  int t = blk & 511;
  int ty0 = (t >> 3) * 4, tx0 = (t & 7) * 32;
  int tid = threadIdx.x;
  int lane = tid & 63;
  int wv = __builtin_amdgcn_readfirstlane(tid >> 6);
  int row = lane >> 4, colg = lane & 15;
  int px0 = colg * 2;
  float acc[2][8];
#pragma unroll
  for (int j = 0; j < 2; ++j)
#pragma unroll
    for (int o = 0; o < 8; ++o) acc[j][o] = bias[wv * 8 + o];
#pragma unroll 1
  for (int ch = 0; ch < 2; ++ch) {
    __syncthreads();
    for (int i = tid; i < 32 * 8 * 36; i += 256) {
      int ic = i / 288;
      int rem = i - ic * 288;
      int r = rem / 36;
      int c = rem - r * 36;
      int gy = ty0 + r - 2, gx = tx0 + c - 2;
      float v = 0.f;
      if ((unsigned)gy < 256u && (unsigned)gx < 256u)
        v = in[(b * 64 + ch * 32 + ic) * HW + gy * 256 + gx];
      sm[ic][r][c] = v;
    }
    __syncthreads();
#pragma unroll 2
    for (int ic = 0; ic < 32; ++ic) {
      const float* wp = wr + ((ch * 32 + ic) * 4 + wv) * 200;
#pragma unroll
      for (int ky = 0; ky < 5; ++ky) {
        const float* srow = &sm[ic][row + ky][px0];
        float win[6];
#pragma unroll
        for (int j = 0; j < 6; ++j) win[j] = srow[j];
#pragma unroll
        for (int kx = 0; kx < 5; ++kx) {
          const float* w8 = wp + (ky * 5 + kx) * 8;
#pragma unroll
          for (int o = 0; o < 8; ++o) {
            float wt = w8[o];
            acc[0][o] = fmaf(win[kx], wt, acc[0][o]);
            acc[1][o] = fmaf(win[kx + 1], wt, acc[1][o]);
          }
        }
      }
    }
  }
  int y = ty0 + row, x = tx0 + px0;
#pragma unroll
  for (int o = 0; o < 8; ++o) {
    float2 r2 = make_float2(lrelu_f(acc[0][o]), lrelu_f(acc[1][o]));
    *(float2*)&out[(b * 32 + wv * 8 + o) * HW + y * 256 + x] = r2;
  }
}

// ---- 1x1 conv 32->3, +1, clip, -> per-pixel sampling params ----
__global__ __launch_bounds__(256) void p2_aff(const float* __restrict__ h2,
                                              const float* __restrict__ w,
                                              const float* __restrict__ bias,
                                              float4* __restrict__ par) {
  int gid = blockIdx.x * 256 + threadIdx.x;  // 131072
  int b = gid >> 16;
  int p = gid & 65535;
  float a0 = bias[0], a1 = bias[1], a2 = bias[2];
  for (int c = 0; c < 32; ++c) {
    float v = h2[(b * 32 + c) * HW + p];
    a0 = fmaf(v, w[c], a0);
    a1 = fmaf(v, w[32 + c], a1);
    a2 = fmaf(v, w[64 + c], a2);
  }
  a0 = fminf(fmaxf(a0 + 1.f, -3.f), 3.f);
  a1 = fminf(fmaxf(a1 + 1.f, -3.f), 3.f);
  a2 = fminf(fmaxf(a2 + 1.f, -3.f), 3.f);
  float th = (a2 - 1.f) * 1.0472f;
  float4 o;
  o.x = a0;
  o.y = a1;
  o.z = cosf(th);
  o.w = sinf(th);
  par[gid] = o;
}

__device__ __forceinline__ int refl_idx(int k) {
  int s = k - 1;
  s = s < 0 ? -s : s;
  s = s > 255 ? 510 - s : s;
  return s;
}

// ---- deformable sampling: thread per (b, cgroup, y, xw); geometry once,
// reused across 8 channels ----
__global__ __launch_bounds__(256) void sample_kernel(const float* __restrict__ x,
                                                     const float4* __restrict__ par,
                                                     float* __restrict__ out) {
  int gid = blockIdx.x * 256 + threadIdx.x;  // 524288
  int xw = gid & 255;
  int y = (gid >> 8) & 255;
  int cg = (gid >> 16) & 3;
  int b = gid >> 18;
  float4 pr = par[(b << 16) + y * 256 + xw];
  float sx = pr.x, sy = pr.y, ct = pr.z, st = pr.w;
  int off[9][4];
  float g[9][4];
#pragma unroll
  for (int ki = 0; ki < 3; ++ki)
#pragma unroll
    for (int kj = 0; kj < 3; ++kj) {
      int n = ki * 3 + kj;
      float px0 = ((float)ki - 1.5f) * sx;
      float py0 = ((float)kj - 1.5f) * sy;
      float px = px0 * ct - py0 * st + 1.5f + (float)(y + 1);
      float py = px0 * st + py0 * ct + 1.5f + (float)(xw + 1);
      float fx = floorf(px), fy = floorf(py);
      float x0f = fminf(fmaxf(fx, 0.f), 257.f);
      float x1f = fminf(fmaxf(fx + 1.f, 0.f), 257.f);
      float y0f = fminf(fmaxf(fy, 0.f), 257.f);
      float y1f = fminf(fmaxf(fy + 1.f, 0.f), 257.f);
      float pxc = fminf(fmaxf(px, 0.f), 257.f);
      float pyc = fminf(fmaxf(py, 0.f), 257.f);
      float dx0 = 1.f + (x0f - pxc), dx1 = 1.f - (x1f - pxc);
      float dy0 = 1.f + (y0f - pyc), dy1 = 1.f - (y1f - pyc);
      g[n][0] = dx0 * dy0;
      g[n][1] = dx1 * dy1;
      g[n][2] = dx0 * dy1;
      g[n][3] = dx1 * dy0;
      int xi0 = refl_idx((int)x0f), xi1 = refl_idx((int)x1f);
      int yi0 = refl_idx((int)y0f), yi1 = refl_idx((int)y1f);
      off[n][0] = xi0 * 256 + yi0;
      off[n][1] = xi1 * 256 + yi1;
      off[n][2] = xi0 * 256 + yi1;
      off[n][3] = xi1 * 256 + yi0;
    }
#pragma unroll 1
  for (int cc = 0; cc < 8; ++cc) {
    int c = cg * 8 + cc;
    const float* xp = x + (size_t)(b * 32 + c) * HW;
    float* op = out + ((size_t)(b * 32 + c) * 768 + 3 * y) * 768 + 3 * xw;
#pragma unroll
    for (int ki = 0; ki < 3; ++ki) {
#pragma unroll
      for (int kj = 0; kj < 3; ++kj) {
        int n = ki * 3 + kj;
        float v = g[n][0] * xp[off[n][0]] + g[n][1] * xp[off[n][1]] +
                  g[n][2] * xp[off[n][2]] + g[n][3] * xp[off[n][3]];
        op[ki * 768 + kj] = v;
      }
    }
  }
}

extern "C" void kernel_launch(void* const* d_in, const int* in_sizes, int n_in,
                              void* d_out, int out_size, void* d_ws, size_t ws_size,
                              hipStream_t stream) {
  const float* x = (const float*)d_in[0];
  const float* query = (const float*)d_in[1];
  const float* ref = (const float*)d_in[2];
  const float* c1_w = (const float*)d_in[3];
  const float* c1_b = (const float*)d_in[4];
  const float* r1a_w = (const float*)d_in[5];
  const float* r1a_b = (const float*)d_in[6];
  const float* r1b_w = (const float*)d_in[7];
  const float* r1b_b = (const float*)d_in[8];
  const float* p1_w = (const float*)d_in[9];
  const float* p1_b = (const float*)d_in[10];
  const float* r2a_w = (const float*)d_in[11];
  const float* r2a_b = (const float*)d_in[12];
  const float* r2b_w = (const float*)d_in[13];
  const float* r2b_b = (const float*)d_in[14];
  const float* p2_w = (const float*)d_in[15];
  const float* p2_b = (const float*)d_in[16];
  float* out = (float*)d_out;

  float* ws = (float*)d_ws;
  float* qup = ws;                        // 393216
  float* cat = qup + 393216;              // 8388608
  float* t1 = cat + 8388608;              // 4194304
  float* t2 = t1 + 4194304;               // 4194304
  float* h1 = t2 + 4194304;               // 4194304
  float4* par = (float4*)(h1 + 4194304);  // 131072 float4
  float* wr_c1 = (float*)(par + 131072);  // 2400
  float* wr_r1a = wr_c1 + 2400;           // 9216
  float* wr_r1b = wr_r1a + 9216;          // 9216
  float* wr_p1 = wr_r1b + 9216;           // 51200
  float* wr_r2a = wr_p1 + 51200;          // 9216
  float* wr_r2b = wr_r2a + 9216;          // 9216

  repack_all<<<354, 256, 0, stream>>>(c1_w, wr_c1, r1a_w, wr_r1a, r1b_w, wr_r1b,
                                      p1_w, wr_p1, r2a_w, wr_r2a, r2b_w, wr_r2b);

  up2_kernel<<<1536, 256, 0, stream>>>(query, qup);

  // head(ref) -> cat channels [0,32)
  conv5_c1<<<1024, 256, 0, stream>>>(ref, wr_c1, c1_b, t1);
  conv3_32<false><<<1024, 256, 0, stream>>>(t1, 32, wr_r1a, r1a_b, nullptr, t2, 32, 0);
  conv3_32<true><<<1024, 256, 0, stream>>>(t2, 32, wr_r1b, r1b_b, t1, cat, 64, 0);

  // head(q_up) -> cat channels [32,64)
  conv5_c1<<<1024, 256, 0, stream>>>(qup, wr_c1, c1_b, t1);
  conv3_32<false><<<1024, 256, 0, stream>>>(t1, 32, wr_r1a, r1a_b, nullptr, t2, 32, 0);
  conv3_32<true><<<1024, 256, 0, stream>>>(t2, 32, wr_r1b, r1b_b, t1, cat, 64, 32);

  // trunk
  conv5_p1<<<1024, 256, 0, stream>>>(cat, wr_p1, p1_b, h1);
  conv3_32<false><<<1024, 256, 0, stream>>>(h1, 32, wr_r2a, r2a_b, nullptr, t2, 32, 0);
  conv3_32<true><<<1024, 256, 0, stream>>>(t2, 32, wr_r2b, r2b_b, h1, t1, 32, 0);

  // affinity params
  p2_aff<<<512, 256, 0, stream>>>(t1, p2_w, p2_b, par);

  // deformable sampling
  sample_kernel<<<2048, 256, 0, stream>>>(x, par, out);
}